// Round 1
// baseline (1184.400 us; speedup 1.0000x reference)
//
#include <hip/hip_runtime.h>

#define BIGV 1e10f

typedef unsigned short ushort_t;
typedef __attribute__((ext_vector_type(8))) short short8;
typedef __attribute__((ext_vector_type(4))) float f32x4;

constexpr int B_ = 64, L_ = 1024, C_ = 64;
constexpr int TN = 16;   // 64x64 tiles per dimension
constexpr int NW = 16;   // waves per block

static __device__ inline ushort_t f2bf(float f) {
  unsigned u = __builtin_bit_cast(unsigned, f);
  unsigned r = (u + 0x7fffu + ((u >> 16) & 1u)) >> 16;
  return (ushort_t)r;
}
static __device__ inline float bf2f(ushort_t us) {
  return __builtin_bit_cast(float, ((unsigned)us) << 16);
}

// Pass 1: convert x,y to bf16 (RNE) and compute row squared-norms in fp32.
__global__ __launch_bounds__(256) void prep_kernel(
    const float* __restrict__ x, const float* __restrict__ y,
    ushort_t* __restrict__ xb, ushort_t* __restrict__ yb,
    float* __restrict__ x2, float* __restrict__ y2)
{
  const int lane = threadIdx.x & 63;
  const int waveg = (blockIdx.x * blockDim.x + threadIdx.x) >> 6;
  const int totalWaves = (gridDim.x * blockDim.x) >> 6;
  const int totalRows = 2 * B_ * L_;
  for (int row = waveg; row < totalRows; row += totalWaves) {
    const float* src; ushort_t* dst; float* nrm; int r;
    if (row < B_ * L_) { r = row;            src = x; dst = xb; nrm = x2; }
    else               { r = row - B_ * L_;  src = y; dst = yb; nrm = y2; }
    float v = src[r * C_ + lane];           // C_ == 64 == wave width
    dst[r * C_ + lane] = f2bf(v);
    float s = v * v;
    #pragma unroll
    for (int off = 32; off > 0; off >>= 1) s += __shfl_down(s, off);
    if (lane == 0) nrm[r] = s;
  }
}

// Pass 2: one block per batch. Tile-wavefront soft-DTW.
// Wave w handles one 64x64 tile per tile-diagonal round:
//   - Gram tile via bf16 MFMA -> D tile (bf16) in per-wave LDS slice
//   - in-register systolic DP (lane = row), shfl_up for up/diag deps
// Cross-tile boundaries: Hbuf (top rows), Vbuf (left cols), CC (corners,
// parity-indexed by tile-row to avoid same-round overwrite).
__global__ __launch_bounds__(1024) void sdtw_kernel(
    const ushort_t* __restrict__ xb, const ushort_t* __restrict__ yb,
    const float* __restrict__ x2g, const float* __restrict__ y2g,
    float* __restrict__ out)
{
  __shared__ ushort_t Dt[NW][64 * 64];
  __shared__ float Hbuf[L_];
  __shared__ float Vbuf[L_];
  __shared__ float CC[2][TN + 1];

  const int b = blockIdx.x;
  const int w = threadIdx.x >> 6;
  const int lane = threadIdx.x & 63;
  const int m = lane & 15, q = lane >> 4;

  const ushort_t* xbB = xb + (size_t)b * L_ * C_;
  const ushort_t* ybB = yb + (size_t)b * L_ * C_;
  const float* x2B = x2g + b * L_;
  const float* y2B = y2g + b * L_;

  for (int t = 0; t < 2 * TN - 1; ++t) {
    int tiLo = t - (TN - 1); if (tiLo < 0) tiLo = 0;
    int tiHi = (t < TN) ? t : TN - 1;
    const bool act = (w < tiHi - tiLo + 1);
    const int ti = tiLo + w;
    const int tj = t - ti;
    const int i0 = ti * 64, j0 = tj * 64;

    // ---- read phase: corners & left boundary (before anyone writes CC) ----
    float cornerIn = BIGV, vleft = BIGV;
    if (act) {
      if (ti == 0)      cornerIn = (tj == 0) ? 0.0f : BIGV;
      else if (tj == 0) cornerIn = BIGV;
      else              cornerIn = CC[ti & 1][tj];
      if (tj > 0) vleft = Vbuf[i0 + lane];
    }
    float diag0 = __shfl_up(vleft, 1);
    if (lane == 0) diag0 = cornerIn;
    __syncthreads();

    if (act) {
      // ---- Gram tile: G = x_tile . y_tile^T (bf16 MFMA) ----
      short8 af[4][2], bfr[4][2];
      #pragma unroll
      for (int mt = 0; mt < 4; ++mt) {
        #pragma unroll
        for (int ks = 0; ks < 2; ++ks) {
          af[mt][ks]  = *(const short8*)(xbB + (size_t)(i0 + mt * 16 + m) * C_ + ks * 32 + q * 8);
          bfr[mt][ks] = *(const short8*)(ybB + (size_t)(j0 + mt * 16 + m) * C_ + ks * 32 + q * 8);
        }
      }
      #pragma unroll
      for (int mt = 0; mt < 4; ++mt) {
        f32x4 x2v = *(const f32x4*)(x2B + i0 + mt * 16 + q * 4);
        #pragma unroll
        for (int nt = 0; nt < 4; ++nt) {
          f32x4 acc = {0.f, 0.f, 0.f, 0.f};
          acc = __builtin_amdgcn_mfma_f32_16x16x32_bf16(af[mt][0], bfr[nt][0], acc, 0, 0, 0);
          acc = __builtin_amdgcn_mfma_f32_16x16x32_bf16(af[mt][1], bfr[nt][1], acc, 0, 0, 0);
          float y2v = y2B[j0 + nt * 16 + m];
          #pragma unroll
          for (int reg = 0; reg < 4; ++reg) {
            float d = x2v[reg] + y2v - 2.0f * acc[reg];
            // C/D layout: row = q*4+reg, col = m  (verified m89)
            Dt[w][(mt * 16 + q * 4 + reg) * 64 + nt * 16 + m] = f2bf(d);
          }
        }
      }

      // ---- in-register systolic DP over the 64x64 tile ----
      const int r = lane;
      const bool hasTop = (ti > 0);
      float cur = 0.f, prevcur = 0.f, hv_last = cornerIn;
      #pragma unroll 1
      for (int s = 0; s < 127; ++s) {
        int c = s - r;
        float up_s = __shfl_up(cur, 1);
        float dg_s = __shfl_up(prevcur, 1);
        float hv = BIGV;
        if (hasTop) hv = Hbuf[j0 + (c & 63)];
        float up = (r == 0) ? hv : up_s;
        float dg = (r == 0) ? hv_last : dg_s;
        float lf = cur;
        if (c == 0) { dg = diag0; lf = vleft; }
        float dv = bf2f(Dt[w][r * 64 + (c & 63)]);
        float mn = fminf(fminf(up, dg), lf);
        float e = __expf(mn - up) + __expf(mn - dg) + __expf(mn - lf);
        float nv = dv + (mn - __logf(e));
        hv_last = hv;
        if (c >= 0 && c < 64) {
          prevcur = cur;
          cur = nv;
          if (r == 63) Hbuf[j0 + c] = nv;   // bottom row -> next tile-row's top
          if (c == 63) Vbuf[i0 + r] = nv;   // right col -> right neighbor's left
        }
      }
      if (lane == 63) {
        CC[(ti + 1) & 1][tj + 1] = cur;     // bottom-right corner, parity slot
        if (ti == TN - 1 && tj == TN - 1) out[b] = cur;  // R[L-1][L-1], gamma=1
      }
    }
    __syncthreads();
  }
}

extern "C" void kernel_launch(void* const* d_in, const int* in_sizes, int n_in,
                              void* d_out, int out_size, void* d_ws, size_t ws_size,
                              hipStream_t stream) {
  const float* x = (const float*)d_in[0];
  const float* y = (const float*)d_in[1];
  float* out = (float*)d_out;

  // ws layout: xb (8MB) | yb (8MB) | x2 (256KB) | y2 (256KB)
  char* ws = (char*)d_ws;
  ushort_t* xb = (ushort_t*)ws;
  ushort_t* yb = (ushort_t*)(ws + (size_t)B_ * L_ * C_ * 2);
  float* x2 = (float*)(ws + (size_t)B_ * L_ * C_ * 4);
  float* y2 = (float*)(ws + (size_t)B_ * L_ * C_ * 4 + (size_t)B_ * L_ * 4);

  prep_kernel<<<512, 256, 0, stream>>>(x, y, xb, yb, x2, y2);
  sdtw_kernel<<<B_, 1024, 0, stream>>>(xb, yb, x2, y2, out);
}